// Round 2
// baseline (1483.297 us; speedup 1.0000x reference)
//
#include <hip/hip_runtime.h>
#include <hip/hip_bf16.h>

typedef __attribute__((ext_vector_type(8))) short bf16x8;
typedef __attribute__((ext_vector_type(4))) float f32x4;
typedef unsigned int u32;
typedef unsigned short u16;

#define MFMA16(a,b,c) __builtin_amdgcn_mfma_f32_16x16x32_bf16((a),(b),(c),0,0,0)

// Problem constants
// B=256, NQ=256, D=512, H=8, DK=DV=64, NK=99, NEW=50, NG=49

__device__ __forceinline__ u16 f2bf(float f){
  u32 u = __float_as_uint(f);
  u += 0x7fffu + ((u >> 16) & 1u);
  return (u16)(u >> 16);
}
__device__ __forceinline__ u32 fenc(float f){
  u32 u = __float_as_uint(f);
  return (u & 0x80000000u) ? ~u : (u | 0x80000000u);
}
__device__ __forceinline__ float fdec2(u32 e){
  u32 u = (e & 0x80000000u) ? (e ^ 0x80000000u) : ~e;
  return __uint_as_float(u);
}

// ---------------- prep kernels ----------------

__global__ void prep_zero(uint4* __restrict__ p, long n16, u32* __restrict__ minslot, u32* __restrict__ flag){
  uint4 z; z.x = 0; z.y = 0; z.z = 0; z.w = 0;
  long stride = (long)gridDim.x * blockDim.x;
  for (long i = (long)blockIdx.x * blockDim.x + threadIdx.x; i < n16; i += stride)
    p[i] = z;
  if (blockIdx.x == 0 && threadIdx.x == 0){
    *minslot = 0x80000000u;  // encode(0.0f)
    *flag = 0u;
  }
}

// mask may be stored as 1-byte bool or 4-byte int. If any byte at index%4!=0
// (within the first 25344 bytes) is nonzero, storage is 1-byte.
__global__ void prep_detect(const unsigned char* __restrict__ m, u32* __restrict__ flag){
  u32 v = 0;
  int stride = gridDim.x * blockDim.x;
  for (int i = blockIdx.x * blockDim.x + threadIdx.x; i < 25344; i += stride)
    if (i & 3) v |= m[i];
  if (v) atomicOr(flag, 1u);
}

__global__ void prep_convert(
  const float* __restrict__ q, const float* __restrict__ k, const float* __restrict__ v,
  const float* __restrict__ w0, const float* __restrict__ w1, const float* __restrict__ w2,
  const float* __restrict__ w3, const float* __restrict__ w4,
  u16* __restrict__ wbf, u16* __restrict__ qcv, u16* __restrict__ kcv, u16* __restrict__ vcv)
{
  const long NW = 1310720, NQe = 33554432, NKe = 19529728, NVe = 12976128;
  long n4 = (NW + NQe + NKe + NVe) >> 2;
  long stride = (long)gridDim.x * blockDim.x;
  for (long i4 = (long)blockIdx.x * blockDim.x + threadIdx.x; i4 < n4; i4 += stride){
    long i = i4 << 2;
    const float* s; u16* d; long lo;
    if (i < NW){
      long sg = i >> 18;
      lo = i & 262143l;
      s = (sg == 0) ? w0 : (sg == 1) ? w1 : (sg == 2) ? w2 : (sg == 3) ? w3 : w4;
      d = wbf + i;
    } else if (i < NW + NQe){
      lo = i - NW; s = q; d = qcv + lo;
    } else if (i < NW + NQe + NKe){
      lo = i - NW - NQe; s = k; d = kcv + lo;
    } else {
      lo = i - NW - NQe - NKe; s = v; d = vcv + lo;
    }
    float4 f = *reinterpret_cast<const float4*>(s + lo);
    ushort4 hv;
    hv.x = f2bf(f.x); hv.y = f2bf(f.y); hv.z = f2bf(f.z); hv.w = f2bf(f.w);
    *reinterpret_cast<ushort4*>(d) = hv;
  }
}

// ---------------- projection GEMM ----------------
// Y = A(bf16, batched rows) @ W^T + bias, stored per-head bf16.
// normal: Y[((b*8+h)*yRO + yrow0 + r)*64 + d]
// transposed (V): Y[((b*8+h)*64 + d)*128 + r]
__global__ __launch_bounds__(256) void gemm_proj(
  const u16* __restrict__ A, long abst, int arow0, int avalid,
  const u16* __restrict__ W, const float* __restrict__ bias,
  u16* __restrict__ Y, int yRO, int yrow0, int tstore)
{
  __shared__ u16 As[128][72];
  __shared__ u16 Bs[128][72];
  int t = threadIdx.x, lane = t & 63, w = t >> 6;
  int wm = w >> 1, wn = w & 1;
  int b = blockIdx.z;
  int bcol = blockIdx.x * 128, brow = blockIdx.y * 128;

  int arow = brow + (t >> 1);
  int arc = min(arow, avalid - 1);
  const u16* Arow = A + (long)b * abst + (long)(arow0 + arc) * 512 + (t & 1) * 32;
  const u16* Wrow = W + (long)(bcol + (t >> 1)) * 512 + (t & 1) * 32;

  f32x4 acc[4][4];
  f32x4 zf; zf[0]=0.f; zf[1]=0.f; zf[2]=0.f; zf[3]=0.f;
  #pragma unroll
  for (int i = 0; i < 4; i++)
    #pragma unroll
    for (int j = 0; j < 4; j++) acc[i][j] = zf;

  for (int kk = 0; kk < 8; kk++){
    bf16x8 av[4], wv[4];
    #pragma unroll
    for (int i = 0; i < 4; i++){
      av[i] = *reinterpret_cast<const bf16x8*>(Arow + kk * 64 + i * 8);
      wv[i] = *reinterpret_cast<const bf16x8*>(Wrow + kk * 64 + i * 8);
    }
    __syncthreads();
    #pragma unroll
    for (int i = 0; i < 4; i++){
      *reinterpret_cast<bf16x8*>(&As[t >> 1][(t & 1) * 32 + i * 8]) = av[i];
      *reinterpret_cast<bf16x8*>(&Bs[t >> 1][(t & 1) * 32 + i * 8]) = wv[i];
    }
    __syncthreads();
    #pragma unroll
    for (int kki = 0; kki < 2; kki++){
      bf16x8 af[4], bfr[4];
      #pragma unroll
      for (int mi = 0; mi < 4; mi++)
        af[mi] = *reinterpret_cast<const bf16x8*>(&As[wm*64 + mi*16 + (lane & 15)][kki*32 + (lane >> 4)*8]);
      #pragma unroll
      for (int ni = 0; ni < 4; ni++)
        bfr[ni] = *reinterpret_cast<const bf16x8*>(&Bs[wn*64 + ni*16 + (lane & 15)][kki*32 + (lane >> 4)*8]);
      #pragma unroll
      for (int mi = 0; mi < 4; mi++)
        #pragma unroll
        for (int ni = 0; ni < 4; ni++)
          acc[mi][ni] = MFMA16(af[mi], bfr[ni], acc[mi][ni]);
    }
  }

  #pragma unroll
  for (int mi = 0; mi < 4; mi++){
    #pragma unroll
    for (int ni = 0; ni < 4; ni++){
      int colt = wn*64 + ni*16 + (lane & 15);
      int col = bcol + colt;
      float bv = bias[col];
      int h = col >> 6, d = col & 63;
      #pragma unroll
      for (int j = 0; j < 4; j++){
        int rowt = wm*64 + mi*16 + (lane >> 4)*4 + j;
        int r = brow + rowt;
        if (r < avalid){
          u16 hb = f2bf(acc[mi][ni][j] + bv);
          if (!tstore) Y[((long)(b*8 + h) * yRO + yrow0 + r) * 64 + d] = hb;
          else         Y[((long)(b*8 + h) * 64 + d) * 128 + r] = hb;
        }
      }
    }
  }
}

// ---------------- output GEMM (f32 out) ----------------
__global__ __launch_bounds__(256) void gemm_out(
  const u16* __restrict__ A, const u16* __restrict__ W,
  const float* __restrict__ bias, float* __restrict__ out)
{
  __shared__ u16 As[128][72];
  __shared__ u16 Bs[128][72];
  int t = threadIdx.x, lane = t & 63, w = t >> 6;
  int wm = w >> 1, wn = w & 1;
  int bcol = blockIdx.x * 128;
  long brow = (long)blockIdx.y * 128;

  const u16* Arow = A + (brow + (t >> 1)) * 512 + (t & 1) * 32;
  const u16* Wrow = W + (long)(bcol + (t >> 1)) * 512 + (t & 1) * 32;

  f32x4 acc[4][4];
  f32x4 zf; zf[0]=0.f; zf[1]=0.f; zf[2]=0.f; zf[3]=0.f;
  #pragma unroll
  for (int i = 0; i < 4; i++)
    #pragma unroll
    for (int j = 0; j < 4; j++) acc[i][j] = zf;

  for (int kk = 0; kk < 8; kk++){
    bf16x8 av[4], wv[4];
    #pragma unroll
    for (int i = 0; i < 4; i++){
      av[i] = *reinterpret_cast<const bf16x8*>(Arow + kk * 64 + i * 8);
      wv[i] = *reinterpret_cast<const bf16x8*>(Wrow + kk * 64 + i * 8);
    }
    __syncthreads();
    #pragma unroll
    for (int i = 0; i < 4; i++){
      *reinterpret_cast<bf16x8*>(&As[t >> 1][(t & 1) * 32 + i * 8]) = av[i];
      *reinterpret_cast<bf16x8*>(&Bs[t >> 1][(t & 1) * 32 + i * 8]) = wv[i];
    }
    __syncthreads();
    #pragma unroll
    for (int kki = 0; kki < 2; kki++){
      bf16x8 af[4], bfr[4];
      #pragma unroll
      for (int mi = 0; mi < 4; mi++)
        af[mi] = *reinterpret_cast<const bf16x8*>(&As[wm*64 + mi*16 + (lane & 15)][kki*32 + (lane >> 4)*8]);
      #pragma unroll
      for (int ni = 0; ni < 4; ni++)
        bfr[ni] = *reinterpret_cast<const bf16x8*>(&Bs[wn*64 + ni*16 + (lane & 15)][kki*32 + (lane >> 4)*8]);
      #pragma unroll
      for (int mi = 0; mi < 4; mi++)
        #pragma unroll
        for (int ni = 0; ni < 4; ni++)
          acc[mi][ni] = MFMA16(af[mi], bfr[ni], acc[mi][ni]);
    }
  }

  #pragma unroll
  for (int mi = 0; mi < 4; mi++){
    #pragma unroll
    for (int ni = 0; ni < 4; ni++){
      int col = bcol + wn*64 + ni*16 + (lane & 15);
      float bv = bias[col];
      #pragma unroll
      for (int j = 0; j < 4; j++){
        long row = brow + wm*64 + mi*16 + (lane >> 4)*4 + j;
        out[row * 512 + col] = acc[mi][ni][j] + bv;
      }
    }
  }
}

// ---------------- S1: global min over masked new_att ----------------
__global__ __launch_bounds__(256) void s1_min(
  const u16* __restrict__ qbf, const u16* __restrict__ kcat,
  const void* __restrict__ maskp, const u32* __restrict__ flagp,
  u32* __restrict__ minslot)
{
  __shared__ u16 Kc[64][72];
  __shared__ unsigned char msk[64];
  __shared__ float wmin[4];
  int t = threadIdx.x, lane = t & 63, w = t >> 6;
  int h = blockIdx.x, b = blockIdx.y;
  long bh = (long)b * 8 + h;

  for (int i = t; i < 64 * 8; i += 256){
    int row = i >> 3, seg = i & 7;
    *reinterpret_cast<bf16x8*>(&Kc[row][seg * 8]) =
      *reinterpret_cast<const bf16x8*>(kcat + (bh * 160 + 96 + row) * 64 + seg * 8);
  }
  u32 flag = *flagp;
  if (t < 50){
    int v = flag ? (((const unsigned char*)maskp)[b * 99 + t] != 0)
                 : (((const int*)maskp)[b * 99 + t] != 0);
    msk[t] = (unsigned char)v;
  }
  __syncthreads();

  bf16x8 af[4][2];
  #pragma unroll
  for (int mi = 0; mi < 4; mi++)
    #pragma unroll
    for (int kki = 0; kki < 2; kki++)
      af[mi][kki] = *reinterpret_cast<const bf16x8*>(
        qbf + (bh * 256 + w * 64 + mi * 16 + (lane & 15)) * 64 + kki * 32 + (lane >> 4) * 8);

  float lmin = 0.f;
  int colb = 96 + (lane & 15);
  f32x4 zf; zf[0]=0.f; zf[1]=0.f; zf[2]=0.f; zf[3]=0.f;
  #pragma unroll
  for (int tt = 0; tt < 4; tt++){
    bf16x8 bf0 = *reinterpret_cast<const bf16x8*>(&Kc[tt*16 + (lane & 15)][(lane >> 4) * 8]);
    bf16x8 bf1 = *reinterpret_cast<const bf16x8*>(&Kc[tt*16 + (lane & 15)][32 + (lane >> 4) * 8]);
    int c = colb + tt * 16;
    bool use = (c >= 99) && (c < 149);
    if (use) use = !msk[c - 99];
    #pragma unroll
    for (int mi = 0; mi < 4; mi++){
      f32x4 acc = zf;
      acc = MFMA16(af[mi][0], bf0, acc);
      acc = MFMA16(af[mi][1], bf1, acc);
      if (use){
        #pragma unroll
        for (int j = 0; j < 4; j++) lmin = fminf(lmin, acc[j] * 0.125f);
      }
    }
  }
  #pragma unroll
  for (int off = 32; off > 0; off >>= 1) lmin = fminf(lmin, __shfl_xor(lmin, off));
  if (lane == 0) wmin[w] = lmin;
  __syncthreads();
  if (t == 0){
    float m = fminf(fminf(wmin[0], wmin[1]), fminf(wmin[2], wmin[3]));
    atomicMin(minslot, fenc(m));
  }
}

// ---------------- S2: fused scores+goatt+softmax+PV ----------------
__global__ __launch_bounds__(256) void s2_fused(
  const u16* __restrict__ qbf, const u16* __restrict__ kcat,
  const u16* __restrict__ vtr, const float* __restrict__ aligns,
  const void* __restrict__ maskp, const u32* __restrict__ flagp,
  const u32* __restrict__ minslot, u16* __restrict__ ctx)
{
  __shared__ float Smat[64][164];
  __shared__ u16 Kc[160][72];
  __shared__ u16 Vt[64][136];
  __shared__ u16 Pm[64][136];
  __shared__ float Al[50][52];
  __shared__ unsigned char msk[100];

  int t = threadIdx.x, lane = t & 63, w = t >> 6;
  int chunk = blockIdx.x, h = blockIdx.y, b = blockIdx.z;
  long bh = (long)b * 8 + h;

  for (int i = t; i < 160 * 8; i += 256){
    int row = i >> 3, seg = i & 7;
    *reinterpret_cast<bf16x8*>(&Kc[row][seg * 8]) =
      *reinterpret_cast<const bf16x8*>(kcat + (bh * 160 + row) * 64 + seg * 8);
  }
  {
    int row = t >> 2, q4 = t & 3;
    #pragma unroll
    for (int i = 0; i < 4; i++){
      int col = q4 * 32 + i * 8;
      *reinterpret_cast<bf16x8*>(&Vt[row][col]) =
        *reinterpret_cast<const bf16x8*>(vtr + (bh * 64 + row) * 128 + col);
    }
  }
  for (int i = t; i < 50 * 49; i += 256){
    Al[i / 49][i % 49] = aligns[(long)b * 2450 + i] * 0.04f;
  }
  u32 flag = *flagp;
  if (t < 99){
    int v = flag ? (((const unsigned char*)maskp)[b * 99 + t] != 0)
                 : (((const int*)maskp)[b * 99 + t] != 0);
    msk[t] = (unsigned char)v;
  }
  float mnew = fdec2(*minslot);
  __syncthreads();

  // phase A: S = (q @ kcat^T) * 0.125 ; 16 q-rows per wave
  {
    int row0 = chunk * 64 + w * 16;
    bf16x8 af[2];
    #pragma unroll
    for (int kki = 0; kki < 2; kki++)
      af[kki] = *reinterpret_cast<const bf16x8*>(
        qbf + (bh * 256 + row0 + (lane & 15)) * 64 + kki * 32 + (lane >> 4) * 8);
    f32x4 zf; zf[0]=0.f; zf[1]=0.f; zf[2]=0.f; zf[3]=0.f;
    #pragma unroll
    for (int tt = 0; tt < 10; tt++){
      f32x4 acc = zf;
      #pragma unroll
      for (int kki = 0; kki < 2; kki++){
        bf16x8 bfr = *reinterpret_cast<const bf16x8*>(&Kc[tt*16 + (lane & 15)][kki*32 + (lane >> 4)*8]);
        acc = MFMA16(af[kki], bfr, acc);
      }
      #pragma unroll
      for (int j = 0; j < 4; j++)
        Smat[w*16 + (lane >> 4)*4 + j][tt*16 + (lane & 15)] = acc[j] * 0.125f;
    }
  }
  __syncthreads();

  // B1: in-place mask / shift. att part: masked -> -inf (global att-min shift is
  // softmax-invariant so it is skipped). new part: masked -> 0 else -= mnew.
  for (int idx = t; idx < 64 * 160; idx += 256){
    int r = idx / 160, c = idx - r * 160;
    if (c < 99){
      if (msk[c]) Smat[r][c] = -INFINITY;
    } else if (c < 149){
      int n = c - 99;
      float v = Smat[r][c];
      Smat[r][c] = msk[n] ? 0.f : (v - mnew);
    }
  }
  __syncthreads();

  // B2: goatt = new_att @ (aligns/25), added into cols 50..98
  for (int idx = t; idx < 64 * 49; idx += 256){
    int r = idx / 49, g = idx - r * 49;
    float a = 0.f;
    for (int n = 0; n < 50; n++) a += Smat[r][99 + n] * Al[n][g];
    Smat[r][50 + g] += a;
  }
  __syncthreads();

  // B3: row softmax over cols 0..98; probs -> Pm (bf16, cols 99..135 zero)
  {
    int r = t >> 2, c0 = t & 3;
    float m = -INFINITY;
    for (int c = c0; c < 99; c += 4) m = fmaxf(m, Smat[r][c]);
    m = fmaxf(m, __shfl_xor(m, 1));
    m = fmaxf(m, __shfl_xor(m, 2));
    float s = 0.f;
    for (int c = c0; c < 99; c += 4){
      float e = __expf(Smat[r][c] - m);
      Smat[r][c] = e;
      s += e;
    }
    s += __shfl_xor(s, 1);
    s += __shfl_xor(s, 2);
    float inv = 1.f / s;
    for (int c = c0; c < 136; c += 4){
      float p = (c < 99) ? Smat[r][c] * inv : 0.f;
      Pm[r][c] = f2bf(p);
    }
  }
  __syncthreads();

  // B5: ctx = P @ V  (V staged transposed: Vt[d][kv])
  {
    bf16x8 pa[4];
    #pragma unroll
    for (int kk = 0; kk < 4; kk++)
      pa[kk] = *reinterpret_cast<const bf16x8*>(&Pm[w*16 + (lane & 15)][kk*32 + (lane >> 4)*8]);
    f32x4 zf; zf[0]=0.f; zf[1]=0.f; zf[2]=0.f; zf[3]=0.f;
    #pragma unroll
    for (int ni = 0; ni < 4; ni++){
      f32x4 acc = zf;
      #pragma unroll
      for (int kk = 0; kk < 4; kk++){
        bf16x8 bv = *reinterpret_cast<const bf16x8*>(&Vt[ni*16 + (lane & 15)][kk*32 + (lane >> 4)*8]);
        acc = MFMA16(pa[kk], bv, acc);
      }
      int d = ni * 16 + (lane & 15);
      #pragma unroll
      for (int j = 0; j < 4; j++){
        int qrow = chunk * 64 + w * 16 + (lane >> 4) * 4 + j;
        ctx[((long)b * 256 + qrow) * 512 + h * 64 + d] = f2bf(acc[j]);
      }
    }
  }
}

// ---------------- launcher ----------------

extern "C" void kernel_launch(void* const* d_in, const int* in_sizes, int n_in,
                              void* d_out, int out_size, void* d_ws, size_t ws_size,
                              hipStream_t stream) {
  (void)in_sizes; (void)n_in; (void)out_size; (void)ws_size;

  const float* queries = (const float*)d_in[0];
  const float* keys    = (const float*)d_in[1];
  const float* values  = (const float*)d_in[2];
  const void*  mask    = d_in[3];
  const float* aligns  = (const float*)d_in[4];
  const float* Wq = (const float*)d_in[5];
  const float* bq = (const float*)d_in[6];
  const float* Wk = (const float*)d_in[7];
  const float* bk = (const float*)d_in[8];
  const float* Wv = (const float*)d_in[9];
  const float* bv = (const float*)d_in[10];
  const float* Wnk = (const float*)d_in[11];
  const float* bnk = (const float*)d_in[12];
  const float* Wo = (const float*)d_in[13];
  const float* bo = (const float*)d_in[14];
  float* out = (float*)d_out;

  u16* WBF  = (u16*)d_ws;                 // 5 * 262144
  u16* QBF  = WBF  + 5l * 262144;         // (B*H, 256, 64)
  u16* KCAT = QBF  + 33554432l;           // (B*H, 160, 64)  rows 0..98 K, 99..148 NK, rest 0
  u16* VTR  = KCAT + 20971520l;           // (B*H, 64, 128)  transposed V, cols>=99 zero
  u16* CTX  = VTR  + 16777216l;           // (B*256, 512)
  u16* QCV  = CTX  + 33554432l;           // bf16 queries
  u16* KCV  = QCV  + 33554432l;           // bf16 keys
  u16* VCV  = KCV  + 19529728l;           // bf16 values
  u32* MINNEW = (u32*)(VCV + 12976128l);
  u32* FLAG   = MINNEW + 1;

  // zero KCAT+VTR (contiguous) + init min/flag
  prep_zero<<<2048, 256, 0, stream>>>((uint4*)KCAT, (20971520l + 16777216l) * 2 / 16, MINNEW, FLAG);
  prep_detect<<<64, 256, 0, stream>>>((const unsigned char*)mask, FLAG);
  prep_convert<<<4096, 256, 0, stream>>>(queries, keys, values, Wq, Wk, Wv, Wnk, Wo,
                                         WBF, QCV, KCV, VCV);

  // projections
  gemm_proj<<<dim3(4, 2, 256), 256, 0, stream>>>(QCV, 131072l, 0, 256, WBF + 0l,        bq,  QBF,  256, 0,  0);
  gemm_proj<<<dim3(4, 1, 256), 256, 0, stream>>>(KCV, 76288l,  0, 99,  WBF + 262144l,   bk,  KCAT, 160, 0,  0);
  gemm_proj<<<dim3(4, 1, 256), 256, 0, stream>>>(KCV, 76288l,  99, 50, WBF + 786432l,   bnk, KCAT, 160, 99, 0);
  gemm_proj<<<dim3(4, 1, 256), 256, 0, stream>>>(VCV, 50688l,  0, 99,  WBF + 524288l,   bv,  VTR,  0,   0,  1);

  // new_att global min
  s1_min<<<dim3(8, 256), 256, 0, stream>>>(QBF, KCAT, mask, FLAG, MINNEW);

  // fused attention
  s2_fused<<<dim3(4, 8, 256), 256, 0, stream>>>(QBF, KCAT, VTR, aligns, mask, FLAG, MINNEW, CTX);

  // output projection
  gemm_out<<<dim3(4, 512), 256, 0, stream>>>(CTX, WBF + 1048576l, bo, out);
}

// Round 5
// 991.898 us; speedup vs baseline: 1.4954x; 1.4954x over previous
//
#include <hip/hip_runtime.h>
#include <hip/hip_bf16.h>

typedef __attribute__((ext_vector_type(8))) short bf16x8;
typedef __attribute__((ext_vector_type(4))) float f32x4;
typedef unsigned int u32;
typedef unsigned short u16;

#define MFMA16(a,b,c) __builtin_amdgcn_mfma_f32_16x16x32_bf16((a),(b),(c),0,0,0)

// B=256, NQ=256, D=512, H=8, DK=DV=64, NK=99, NEW=50, NG=49

__device__ __forceinline__ u16 f2bf(float f){
  u32 u = __float_as_uint(f);
  u += 0x7fffu + ((u >> 16) & 1u);
  return (u16)(u >> 16);
}
__device__ __forceinline__ float bf2f(u16 h){
  return __uint_as_float(((u32)h) << 16);
}
__device__ __forceinline__ u32 fenc(float f){
  u32 u = __float_as_uint(f);
  return (u & 0x80000000u) ? ~u : (u | 0x80000000u);
}
__device__ __forceinline__ float fdec2(u32 e){
  u32 u = (e & 0x80000000u) ? (e ^ 0x80000000u) : ~e;
  return __uint_as_float(u);
}
__device__ __forceinline__ bf16x8 cvt8(const float* p){
  float4 a = *reinterpret_cast<const float4*>(p);
  float4 b = *reinterpret_cast<const float4*>(p + 4);
  bf16x8 r;
  r[0] = (short)f2bf(a.x); r[1] = (short)f2bf(a.y);
  r[2] = (short)f2bf(a.z); r[3] = (short)f2bf(a.w);
  r[4] = (short)f2bf(b.x); r[5] = (short)f2bf(b.y);
  r[6] = (short)f2bf(b.z); r[7] = (short)f2bf(b.w);
  return r;
}

// ---------------- prep kernels ----------------

__global__ void prep_init(u32* __restrict__ minslot, u32* __restrict__ flag){
  if (threadIdx.x == 0){ *minslot = 0x80000000u; *flag = 0u; }  // encode(0.0f)
}

// mask may be stored as 1-byte bool or 4-byte int.
__global__ void prep_detect(const unsigned char* __restrict__ m, u32* __restrict__ flag){
  u32 v = 0;
  int stride = gridDim.x * blockDim.x;
  for (int i = blockIdx.x * blockDim.x + threadIdx.x; i < 25344; i += stride)
    if (i & 3) v |= m[i];
  if (v) atomicOr(flag, 1u);
}

// convert the 5 weight matrices (each 262144 f32) to bf16
__global__ void prep_convert_w(
  const float* __restrict__ w0, const float* __restrict__ w1, const float* __restrict__ w2,
  const float* __restrict__ w3, const float* __restrict__ w4, u16* __restrict__ wbf)
{
  long n4 = (5l * 262144) >> 2;
  long stride = (long)gridDim.x * blockDim.x;
  for (long i4 = (long)blockIdx.x * blockDim.x + threadIdx.x; i4 < n4; i4 += stride){
    long i = i4 << 2;
    long sg = i >> 18, lo = i & 262143l;
    const float* s = (sg == 0) ? w0 : (sg == 1) ? w1 : (sg == 2) ? w2 : (sg == 3) ? w3 : w4;
    float4 f = *reinterpret_cast<const float4*>(s + lo);
    ushort4 hv;
    hv.x = f2bf(f.x); hv.y = f2bf(f.y); hv.z = f2bf(f.z); hv.w = f2bf(f.w);
    *reinterpret_cast<ushort4*>(wbf + i) = hv;
  }
}

// ---------------- projection GEMM (A f32 -> staged bf16, W bf16) ----------------
// Y = A @ W^T + bias, per-head bf16 store.
// normal: Y[((b*8+h)*yRO + yrow0 + r)*64 + d]
// transposed (V): Y[((b*8+h)*64 + d)*128 + r]
__global__ __launch_bounds__(256) void gemm_proj(
  const float* __restrict__ A, long abst, int arow0, int avalid,
  const u16* __restrict__ W, const float* __restrict__ bias,
  u16* __restrict__ Y, int yRO, int yrow0, int tstore)
{
  __shared__ u16 As[128][72];
  __shared__ u16 Bs[128][72];
  int t = threadIdx.x, lane = t & 63, w = t >> 6;
  int wm = w >> 1, wn = w & 1;
  int b = blockIdx.z;
  int bcol = blockIdx.x * 128, brow = blockIdx.y * 128;

  int arow = brow + (t >> 1);
  int arc = min(arow, avalid - 1);
  const float* Arow = A + (long)b * abst + (long)(arow0 + arc) * 512 + (t & 1) * 32;
  const u16*   Wrow = W + (long)(bcol + (t >> 1)) * 512 + (t & 1) * 32;

  f32x4 acc[4][4];
  f32x4 zf; zf[0]=0.f; zf[1]=0.f; zf[2]=0.f; zf[3]=0.f;
  #pragma unroll
  for (int i = 0; i < 4; i++)
    #pragma unroll
    for (int j = 0; j < 4; j++) acc[i][j] = zf;

  for (int kk = 0; kk < 8; kk++){
    bf16x8 av[4], wv[4];
    #pragma unroll
    for (int i = 0; i < 4; i++){
      av[i] = cvt8(Arow + kk * 64 + i * 8);
      wv[i] = *reinterpret_cast<const bf16x8*>(Wrow + kk * 64 + i * 8);
    }
    __syncthreads();
    #pragma unroll
    for (int i = 0; i < 4; i++){
      *reinterpret_cast<bf16x8*>(&As[t >> 1][(t & 1) * 32 + i * 8]) = av[i];
      *reinterpret_cast<bf16x8*>(&Bs[t >> 1][(t & 1) * 32 + i * 8]) = wv[i];
    }
    __syncthreads();
    #pragma unroll
    for (int kki = 0; kki < 2; kki++){
      bf16x8 af[4], bfr[4];
      #pragma unroll
      for (int mi = 0; mi < 4; mi++)
        af[mi] = *reinterpret_cast<const bf16x8*>(&As[wm*64 + mi*16 + (lane & 15)][kki*32 + (lane >> 4)*8]);
      #pragma unroll
      for (int ni = 0; ni < 4; ni++)
        bfr[ni] = *reinterpret_cast<const bf16x8*>(&Bs[wn*64 + ni*16 + (lane & 15)][kki*32 + (lane >> 4)*8]);
      #pragma unroll
      for (int mi = 0; mi < 4; mi++)
        #pragma unroll
        for (int ni = 0; ni < 4; ni++)
          acc[mi][ni] = MFMA16(af[mi], bfr[ni], acc[mi][ni]);
    }
  }

  #pragma unroll
  for (int mi = 0; mi < 4; mi++){
    #pragma unroll
    for (int ni = 0; ni < 4; ni++){
      int colt = wn*64 + ni*16 + (lane & 15);
      int col = bcol + colt;
      float bv = bias[col];
      int h = col >> 6, d = col & 63;
      #pragma unroll
      for (int j = 0; j < 4; j++){
        int rowt = wm*64 + mi*16 + (lane >> 4)*4 + j;
        int r = brow + rowt;
        if (r < avalid){
          u16 hb = f2bf(acc[mi][ni][j] + bv);
          if (!tstore) Y[((long)(b*8 + h) * yRO + yrow0 + r) * 64 + d] = hb;
          else         Y[((long)(b*8 + h) * 64 + d) * 128 + r] = hb;
        }
      }
    }
  }
}

// ---------------- output GEMM (A bf16, W bf16, f32 out) ----------------
__global__ __launch_bounds__(256) void gemm_out(
  const u16* __restrict__ A, const u16* __restrict__ W,
  const float* __restrict__ bias, float* __restrict__ out)
{
  __shared__ u16 As[128][72];
  __shared__ u16 Bs[128][72];
  int t = threadIdx.x, lane = t & 63, w = t >> 6;
  int wm = w >> 1, wn = w & 1;
  int bcol = blockIdx.x * 128;
  long brow = (long)blockIdx.y * 128;

  const u16* Arow = A + (brow + (t >> 1)) * 512 + (t & 1) * 32;
  const u16* Wrow = W + (long)(bcol + (t >> 1)) * 512 + (t & 1) * 32;

  f32x4 acc[4][4];
  f32x4 zf; zf[0]=0.f; zf[1]=0.f; zf[2]=0.f; zf[3]=0.f;
  #pragma unroll
  for (int i = 0; i < 4; i++)
    #pragma unroll
    for (int j = 0; j < 4; j++) acc[i][j] = zf;

  for (int kk = 0; kk < 8; kk++){
    bf16x8 av[4], wv[4];
    #pragma unroll
    for (int i = 0; i < 4; i++){
      av[i] = *reinterpret_cast<const bf16x8*>(Arow + kk * 64 + i * 8);
      wv[i] = *reinterpret_cast<const bf16x8*>(Wrow + kk * 64 + i * 8);
    }
    __syncthreads();
    #pragma unroll
    for (int i = 0; i < 4; i++){
      *reinterpret_cast<bf16x8*>(&As[t >> 1][(t & 1) * 32 + i * 8]) = av[i];
      *reinterpret_cast<bf16x8*>(&Bs[t >> 1][(t & 1) * 32 + i * 8]) = wv[i];
    }
    __syncthreads();
    #pragma unroll
    for (int kki = 0; kki < 2; kki++){
      bf16x8 af[4], bfr[4];
      #pragma unroll
      for (int mi = 0; mi < 4; mi++)
        af[mi] = *reinterpret_cast<const bf16x8*>(&As[wm*64 + mi*16 + (lane & 15)][kki*32 + (lane >> 4)*8]);
      #pragma unroll
      for (int ni = 0; ni < 4; ni++)
        bfr[ni] = *reinterpret_cast<const bf16x8*>(&Bs[wn*64 + ni*16 + (lane & 15)][kki*32 + (lane >> 4)*8]);
      #pragma unroll
      for (int mi = 0; mi < 4; mi++)
        #pragma unroll
        for (int ni = 0; ni < 4; ni++)
          acc[mi][ni] = MFMA16(af[mi], bfr[ni], acc[mi][ni]);
    }
  }

  #pragma unroll
  for (int mi = 0; mi < 4; mi++){
    #pragma unroll
    for (int ni = 0; ni < 4; ni++){
      int col = bcol + wn*64 + ni*16 + (lane & 15);
      float bv = bias[col];
      #pragma unroll
      for (int j = 0; j < 4; j++){
        long row = brow + wm*64 + mi*16 + (lane >> 4)*4 + j;
        out[row * 512 + col] = acc[mi][ni][j] + bv;
      }
    }
  }
}

// ---------------- S1: global min over unmasked new_att ----------------
__global__ __launch_bounds__(256) void s1_min(
  const u16* __restrict__ qbf, const u16* __restrict__ kcat,
  const void* __restrict__ maskp, const u32* __restrict__ flagp,
  u32* __restrict__ minslot)
{
  __shared__ u16 Kc[64][72];
  __shared__ unsigned char msk[64];
  __shared__ float wmin[4];
  int t = threadIdx.x, lane = t & 63, w = t >> 6;
  int h = blockIdx.x, b = blockIdx.y;
  long bh = (long)b * 8 + h;

  for (int i = t; i < 64 * 8; i += 256){
    int row = i >> 3, seg = i & 7;
    *reinterpret_cast<bf16x8*>(&Kc[row][seg * 8]) =
      *reinterpret_cast<const bf16x8*>(kcat + (bh * 160 + 96 + row) * 64 + seg * 8);
  }
  u32 flag = *flagp;
  if (t < 50){
    int v = flag ? (((const unsigned char*)maskp)[b * 99 + t] != 0)
                 : (((const int*)maskp)[b * 99 + t] != 0);
    msk[t] = (unsigned char)v;
  }
  __syncthreads();

  bf16x8 af[4][2];
  #pragma unroll
  for (int mi = 0; mi < 4; mi++)
    #pragma unroll
    for (int kki = 0; kki < 2; kki++)
      af[mi][kki] = *reinterpret_cast<const bf16x8*>(
        qbf + (bh * 256 + w * 64 + mi * 16 + (lane & 15)) * 64 + kki * 32 + (lane >> 4) * 8);

  float lmin = 0.f;
  int colb = 96 + (lane & 15);
  f32x4 zf; zf[0]=0.f; zf[1]=0.f; zf[2]=0.f; zf[3]=0.f;
  #pragma unroll
  for (int tt = 0; tt < 4; tt++){
    bf16x8 bf0 = *reinterpret_cast<const bf16x8*>(&Kc[tt*16 + (lane & 15)][(lane >> 4) * 8]);
    bf16x8 bf1 = *reinterpret_cast<const bf16x8*>(&Kc[tt*16 + (lane & 15)][32 + (lane >> 4) * 8]);
    int c = colb + tt * 16;
    bool use = (c >= 99) && (c < 149);
    if (use) use = !msk[c - 99];
    #pragma unroll
    for (int mi = 0; mi < 4; mi++){
      f32x4 acc = zf;
      acc = MFMA16(af[mi][0], bf0, acc);
      acc = MFMA16(af[mi][1], bf1, acc);
      if (use){
        #pragma unroll
        for (int j = 0; j < 4; j++) lmin = fminf(lmin, acc[j] * 0.125f);
      }
    }
  }
  #pragma unroll
  for (int off = 32; off > 0; off >>= 1) lmin = fminf(lmin, __shfl_xor(lmin, off));
  if (lane == 0) wmin[w] = lmin;
  __syncthreads();
  if (t == 0){
    float m = fminf(fminf(wmin[0], wmin[1]), fminf(wmin[2], wmin[3]));
    atomicMin(minslot, fenc(m));
  }
}

// ---------------- S2: fused scores+goatt+softmax+PV (wave-local) ----------------
// LDS: Smat f32 [64][101] (att logits, cols 0..98)
//      AlB bf16 hi/lo [2][64 g][72 n] (B-layout aligns*0.04)
//      U: union of NA bf16 hi/lo [2][64 r][72 n] and Pm bf16 [64][136]
__global__ __launch_bounds__(256) void s2_fused(
  const u16* __restrict__ qbf, const u16* __restrict__ kcat,
  const u16* __restrict__ vtr, const float* __restrict__ aligns,
  const void* __restrict__ maskp, const u32* __restrict__ flagp,
  const u32* __restrict__ minslot, u16* __restrict__ ctx)
{
  __shared__ float Smat[64][101];
  __shared__ u16 AlB[2][64][72];
  __shared__ u16 U[9216];
  __shared__ unsigned char msk[100];

  int t = threadIdx.x, lane = t & 63, w = t >> 6;
  int chunk = blockIdx.x, h = blockIdx.y, b = blockIdx.z;
  long bh = (long)b * 8 + h;

  // ---- staging ----
  for (int i = t; i < 64 * 72; i += 256){
    int g = i / 72, n = i - g * 72;
    float val = (g < 49 && n < 50) ? aligns[(long)b * 2450 + n * 49 + g] * 0.04f : 0.f;
    u16 hi = f2bf(val);
    AlB[0][g][n] = hi;
    AlB[1][g][n] = f2bf(val - bf2f(hi));
  }
  // zero NA pad columns n in [50,72)
  for (int i = t; i < 2 * 64 * 22; i += 256){
    int s = i / 1408, rem = i - s * 1408;
    int r = rem / 22, c = 50 + (rem - r * 22);
    U[s * 4608 + r * 72 + c] = 0;
  }
  u32 flag = *flagp;
  if (t < 99){
    int v = flag ? (((const unsigned char*)maskp)[b * 99 + t] != 0)
                 : (((const int*)maskp)[b * 99 + t] != 0);
    msk[t] = (unsigned char)v;
  }
  float mnew = fdec2(*minslot);
  __syncthreads();

  f32x4 zf; zf[0]=0.f; zf[1]=0.f; zf[2]=0.f; zf[3]=0.f;
  int l15 = lane & 15, lh = lane >> 4;
  int rbase = w * 16 + lh * 4;

  // ---- phase A: S = (q @ kcat^T) * 0.125 ; fold mask / -inf / min-shift ----
  {
    int row0 = chunk * 64 + w * 16;
    bf16x8 af[2];
    #pragma unroll
    for (int kki = 0; kki < 2; kki++)
      af[kki] = *reinterpret_cast<const bf16x8*>(
        qbf + (bh * 256 + row0 + l15) * 64 + kki * 32 + lh * 8);
    #pragma unroll
    for (int tt = 0; tt < 10; tt++){
      f32x4 acc = zf;
      #pragma unroll
      for (int kki = 0; kki < 2; kki++){
        bf16x8 bfr = *reinterpret_cast<const bf16x8*>(
          kcat + (bh * 160 + tt * 16 + l15) * 64 + kki * 32 + lh * 8);
        acc = MFMA16(af[kki], bfr, acc);
      }
      int col = tt * 16 + l15;
      if (col < 99){
        bool mm = msk[col] != 0;
        #pragma unroll
        for (int j = 0; j < 4; j++)
          Smat[rbase + j][col] = mm ? -INFINITY : acc[j] * 0.125f;
      } else if (col < 149){
        int n = col - 99;
        bool mm = msk[n] != 0;
        #pragma unroll
        for (int j = 0; j < 4; j++){
          float na = mm ? 0.f : (acc[j] * 0.125f - mnew);
          u16 hi = f2bf(na);
          U[(rbase + j) * 72 + n] = hi;
          U[4608 + (rbase + j) * 72 + n] = f2bf(na - bf2f(hi));
        }
      }
    }
  }

  // ---- B2: goatt = NA @ AlB (split precision), added into Smat cols 50..98 ----
  {
    int arow = w * 16 + l15;
    bf16x8 pah[2], pal[2];
    #pragma unroll
    for (int kki = 0; kki < 2; kki++){
      pah[kki] = *reinterpret_cast<const bf16x8*>(&U[arow * 72 + kki * 32 + lh * 8]);
      pal[kki] = *reinterpret_cast<const bf16x8*>(&U[4608 + arow * 72 + kki * 32 + lh * 8]);
    }
    #pragma unroll
    for (int gt = 0; gt < 4; gt++){
      f32x4 acc = zf;
      #pragma unroll
      for (int kki = 0; kki < 2; kki++){
        bf16x8 bh_ = *reinterpret_cast<const bf16x8*>(&AlB[0][gt*16 + l15][kki*32 + lh*8]);
        bf16x8 bl_ = *reinterpret_cast<const bf16x8*>(&AlB[1][gt*16 + l15][kki*32 + lh*8]);
        acc = MFMA16(pah[kki], bh_, acc);
        acc = MFMA16(pal[kki], bh_, acc);
        acc = MFMA16(pah[kki], bl_, acc);
      }
      int g = gt * 16 + l15;
      if (g < 49){
        #pragma unroll
        for (int j = 0; j < 4; j++)
          Smat[rbase + j][50 + g] += acc[j];
      }
    }
  }
  __syncthreads();  // NA (in U) dead after this point; Pm aliases it across waves

  // ---- B3: row softmax over cols 0..98 -> Pm bf16 (cols 99..135 zero) ----
  {
    int r = w * 16 + l15, c0 = lh;
    float m = -INFINITY;
    for (int c = c0; c < 99; c += 4) m = fmaxf(m, Smat[r][c]);
    m = fmaxf(m, __shfl_xor(m, 16));
    m = fmaxf(m, __shfl_xor(m, 32));
    float s = 0.f;
    for (int c = c0; c < 99; c += 4){
      float e = __expf(Smat[r][c] - m);
      Smat[r][c] = e;
      s += e;
    }
    s += __shfl_xor(s, 16);
    s += __shfl_xor(s, 32);
    float inv = 1.f / s;
    for (int c = c0; c < 136; c += 4){
      float p = (c < 99) ? Smat[r][c] * inv : 0.f;
      U[r * 136 + c] = f2bf(p);
    }
  }

  // ---- PV: ctx = P @ V (V fragments direct from global, [d][kv] layout) ----
  {
    bf16x8 pa[4];
    #pragma unroll
    for (int kk = 0; kk < 4; kk++)
      pa[kk] = *reinterpret_cast<const bf16x8*>(&U[(w*16 + l15) * 136 + kk*32 + lh*8]);
    #pragma unroll
    for (int ni = 0; ni < 4; ni++){
      f32x4 acc = zf;
      #pragma unroll
      for (int kk = 0; kk < 4; kk++){
        bf16x8 bv = *reinterpret_cast<const bf16x8*>(
          vtr + (bh * 64 + ni * 16 + l15) * 128 + kk * 32 + lh * 8);
        acc = MFMA16(pa[kk], bv, acc);
      }
      int d = ni * 16 + l15;
      #pragma unroll
      for (int j = 0; j < 4; j++){
        int qrow = chunk * 64 + rbase + j;
        ctx[((long)b * 256 + qrow) * 512 + h * 64 + d] = f2bf(acc[j]);
      }
    }
  }
}

// ---------------- launcher ----------------

extern "C" void kernel_launch(void* const* d_in, const int* in_sizes, int n_in,
                              void* d_out, int out_size, void* d_ws, size_t ws_size,
                              hipStream_t stream) {
  (void)in_sizes; (void)n_in; (void)out_size; (void)ws_size;

  const float* queries = (const float*)d_in[0];
  const float* keys    = (const float*)d_in[1];
  const float* values  = (const float*)d_in[2];
  const void*  mask    = d_in[3];
  const float* aligns  = (const float*)d_in[4];
  const float* Wq = (const float*)d_in[5];
  const float* bq = (const float*)d_in[6];
  const float* Wk = (const float*)d_in[7];
  const float* bk = (const float*)d_in[8];
  const float* Wv = (const float*)d_in[9];
  const float* bv = (const float*)d_in[10];
  const float* Wnk = (const float*)d_in[11];
  const float* bnk = (const float*)d_in[12];
  const float* Wo = (const float*)d_in[13];
  const float* bo = (const float*)d_in[14];
  float* out = (float*)d_out;

  u16* WBF  = (u16*)d_ws;                 // 5 * 262144 bf16 weights
  u16* QBF  = WBF  + 5l * 262144;         // (B*H, 256, 64)
  u16* KCAT = QBF  + 33554432l;           // (B*H, 160, 64) rows 0..98 K, 99..148 NK, 149.. garbage(unused)
  u16* VTR  = KCAT + 20971520l;           // (B*H, 64, 128) V transposed, cols>=99 garbage (x0 in PV)
  u16* CTX  = VTR  + 16777216l;           // (B*256, 512)
  u32* MINNEW = (u32*)(CTX + 33554432l);
  u32* FLAG   = MINNEW + 1;

  prep_init<<<1, 64, 0, stream>>>(MINNEW, FLAG);
  prep_detect<<<64, 256, 0, stream>>>((const unsigned char*)mask, FLAG);
  prep_convert_w<<<640, 256, 0, stream>>>(Wq, Wk, Wv, Wnk, Wo, WBF);

  // projections (A f32 read directly, converted in staging)
  gemm_proj<<<dim3(4, 2, 256), 256, 0, stream>>>(queries, 131072l, 0, 256, WBF + 0l,      bq,  QBF,  256, 0,  0);
  gemm_proj<<<dim3(4, 1, 256), 256, 0, stream>>>(keys,    76288l,  0, 99,  WBF + 262144l, bk,  KCAT, 160, 0,  0);
  gemm_proj<<<dim3(4, 1, 256), 256, 0, stream>>>(keys,    76288l,  99, 50, WBF + 786432l, bnk, KCAT, 160, 99, 0);
  gemm_proj<<<dim3(4, 1, 256), 256, 0, stream>>>(values,  50688l,  0, 99,  WBF + 524288l, bv,  VTR,  0,   0,  1);

  // new_att global min
  s1_min<<<dim3(8, 256), 256, 0, stream>>>(QBF, KCAT, mask, FLAG, MINNEW);

  // fused attention
  s2_fused<<<dim3(4, 8, 256), 256, 0, stream>>>(QBF, KCAT, VTR, aligns, mask, FLAG, MINNEW, CTX);

  // output projection
  gemm_out<<<dim3(4, 512), 256, 0, stream>>>(CTX, WBF + 1048576l, bo, out);
}